// Round 1
// baseline (39.276 us; speedup 1.0000x reference)
//
#include <hip/hip_runtime.h>

// Problem constants (KnnLinearFixModel): B=512, K=64, D=1024, L=8, 20 SGD steps.
// Key identity: W_t = c^t*W0 + A_t*X  (c = 1-LR*WD), so only G=X*X^T, M0=X*W0^T,
// q=X*e, p0=W0*e are needed; the 20-step loop runs on 64x8 matrices on-chip.

#define BB 512
#define KK 64
#define DD 1024
#define LL 8
#define NSTEPS 20

typedef __attribute__((ext_vector_type(8))) short bf16x8;
typedef __attribute__((ext_vector_type(4))) float f32x4;

__device__ __forceinline__ short f2bf(float f) {
    // round-to-nearest-even f32 -> bf16 (inputs are finite Gaussians; no NaN handling)
    unsigned u = __float_as_uint(f);
    unsigned r = (u + 0x7FFFu + ((u >> 16) & 1u)) >> 16;
    return (short)r;
}

__global__ __launch_bounds__(256, 2)
void knn_linear_fix_kernel(const float* __restrict__ demo,   // [B,K,D]
                           const float* __restrict__ emb,    // [B,D]
                           const float* __restrict__ W0,     // [B,L,D]
                           const float* __restrict__ b0,     // [B,L]
                           const int*   __restrict__ labels, // [B,K]
                           float* __restrict__ out)          // [B,L]
{
    const int b    = blockIdx.x;
    const int t    = threadIdx.x;
    const int lane = t & 63;
    const int wid  = t >> 6;          // wave id 0..3
    const int lg   = lane >> 4;       // lane group 0..3
    const int lr   = lane & 15;       // low lane bits -> row (A) / col (B,C)

    const float LR  = 1e-4f;
    const float WD  = 0.01f;
    const float LRS = LR * (2.0f / (float)(KK * LL)); // LR*scale = 3.90625e-7
    const float CD  = 1.0f - LR * WD;                 // weight-decay contraction

    // LDS: stride 72 shorts (=144 B) breaks the 128B-stride bank pathology (2-way max)
    __shared__ short Xs[64 * 72];   // X chunk, bf16
    __shared__ short Ps[16 * 72];   // [W0 rows (8); e (1); zeros (7)] chunk, bf16
    __shared__ short Gs[64 * 72];   // G = X X^T, bf16
    __shared__ short Ss[16 * 72];   // S^T: [col][k-row], bf16
    __shared__ float red[256];      // cross-wave reduction buffer [16 groups][16 cols]
    __shared__ float b_s[16];       // bias state (cols 8..15 padding = 0)
    __shared__ float p0_s[16];      // p0 = W0 . e
    __shared__ float q_s[64];       // q  = X . e
    __shared__ int   lab_s[64];

    const float* Xg = demo + (size_t)b * (KK * DD);
    const float* Wg = W0   + (size_t)b * (LL * DD);
    const float* eg = emb  + (size_t)b * DD;

    if (t < 64) lab_s[t] = labels[b * KK + t];
    if (t < 16) b_s[t] = (t < 8) ? b0[b * LL + t] : 0.0f;
    for (int i = t; i < 16 * 72; i += 256) Ss[i] = 0;

    // Gram accumulators: wave w owns G rows [16w,16w+16) x all 64 cols (4 tiles),
    // plus M tile (cols: 0..7 = M0, 8 = q) and the redundant P*P^T tile (for p0).
    f32x4 accG0 = {0,0,0,0}, accG1 = {0,0,0,0}, accG2 = {0,0,0,0}, accG3 = {0,0,0,0};
    f32x4 accM  = {0,0,0,0}, accPP = {0,0,0,0};

    // ---------------- Phase 1: stream D in chunks of 64, accumulate Gram products
    for (int ch = 0; ch < DD / 64; ++ch) {
        const int dk = ch * 64;
        #pragma unroll
        for (int i = 0; i < 4; ++i) {             // X chunk: 64x64 f32 -> bf16 LDS
            const int row = i * 16 + (t >> 4);
            const int col = (t & 15) * 4;
            const float4 v = *(const float4*)(Xg + (size_t)row * DD + dk + col);
            short4 h;
            h.x = f2bf(v.x); h.y = f2bf(v.y); h.z = f2bf(v.z); h.w = f2bf(v.w);
            *(short4*)(&Xs[row * 72 + col]) = h;
        }
        {                                          // P chunk: 16x64
            const int row = t >> 4;
            const int col = (t & 15) * 4;
            float4 v = make_float4(0.f, 0.f, 0.f, 0.f);
            if (row < 8)       v = *(const float4*)(Wg + (size_t)row * DD + dk + col);
            else if (row == 8) v = *(const float4*)(eg + dk + col);
            short4 h;
            h.x = f2bf(v.x); h.y = f2bf(v.y); h.z = f2bf(v.z); h.w = f2bf(v.w);
            *(short4*)(&Ps[row * 72 + col]) = h;
        }
        __syncthreads();
        #pragma unroll
        for (int ks = 0; ks < 2; ++ks) {
            const int ko = ks * 32 + lg * 8;
            // a-frag and b-frag are the same load function for Gram products:
            // any consistent k-permutation inside the MFMA cancels.
            const bf16x8 fa = *(const bf16x8*)(&Xs[(wid * 16 + lr) * 72 + ko]);
            const bf16x8 f0 = *(const bf16x8*)(&Xs[( 0 + lr) * 72 + ko]);
            const bf16x8 f1 = *(const bf16x8*)(&Xs[(16 + lr) * 72 + ko]);
            const bf16x8 f2 = *(const bf16x8*)(&Xs[(32 + lr) * 72 + ko]);
            const bf16x8 f3 = *(const bf16x8*)(&Xs[(48 + lr) * 72 + ko]);
            const bf16x8 fp = *(const bf16x8*)(&Ps[lr * 72 + ko]);
            accG0 = __builtin_amdgcn_mfma_f32_16x16x32_bf16(fa, f0, accG0, 0, 0, 0);
            accG1 = __builtin_amdgcn_mfma_f32_16x16x32_bf16(fa, f1, accG1, 0, 0, 0);
            accG2 = __builtin_amdgcn_mfma_f32_16x16x32_bf16(fa, f2, accG2, 0, 0, 0);
            accG3 = __builtin_amdgcn_mfma_f32_16x16x32_bf16(fa, f3, accG3, 0, 0, 0);
            accM  = __builtin_amdgcn_mfma_f32_16x16x32_bf16(fa, fp, accM , 0, 0, 0);
            accPP = __builtin_amdgcn_mfma_f32_16x16x32_bf16(fp, fp, accPP, 0, 0, 0);
        }
        __syncthreads();
    }

    // ---------------- Phase 2: spill G (bf16), q, p0; C/D layout: row=(lg*4+r), col=lr
    #pragma unroll
    for (int r = 0; r < 4; ++r) {
        const int row = wid * 16 + lg * 4 + r;
        Gs[row * 72 +  0 + lr] = f2bf(accG0[r]);
        Gs[row * 72 + 16 + lr] = f2bf(accG1[r]);
        Gs[row * 72 + 32 + lr] = f2bf(accG2[r]);
        Gs[row * 72 + 48 + lr] = f2bf(accG3[r]);
    }
    if (lr == 8) {
        #pragma unroll
        for (int r = 0; r < 4; ++r) q_s[wid * 16 + lg * 4 + r] = accM[r];
    }
    if (wid == 0 && lg == 2) p0_s[lr] = accPP[0];   // row 8 of P*P^T = e . P[col]
    __syncthreads();

    // ---------------- Phase 3: 20-step SGD on 64x8 state, out = c^t*M0 + G*S + b
    const bf16x8 ga0 = *(const bf16x8*)(&Gs[(wid * 16 + lr) * 72 +  0 + lg * 8]);
    const bf16x8 ga1 = *(const bf16x8*)(&Gs[(wid * 16 + lr) * 72 + 32 + lg * 8]);

    const int row0 = wid * 16 + lg * 4;
    const float yv0 = (lab_s[row0 + 0] == lr) ? 1.0f : 0.0f;
    const float yv1 = (lab_s[row0 + 1] == lr) ? 1.0f : 0.0f;
    const float yv2 = (lab_s[row0 + 2] == lr) ? 1.0f : 0.0f;
    const float yv3 = (lab_s[row0 + 3] == lr) ? 1.0f : 0.0f;

    const float m00 = accM[0], m01 = accM[1], m02 = accM[2], m03 = accM[3];
    float s0 = 0.f, s1 = 0.f, s2 = 0.f, s3 = 0.f;
    float ct = 1.0f;

    for (int step = 0; step < NSTEPS; ++step) {
        const bf16x8 sb0 = *(const bf16x8*)(&Ss[lr * 72 +  0 + lg * 8]);
        const bf16x8 sb1 = *(const bf16x8*)(&Ss[lr * 72 + 32 + lg * 8]);
        f32x4 o = {0.f, 0.f, 0.f, 0.f};
        o = __builtin_amdgcn_mfma_f32_16x16x32_bf16(ga0, sb0, o, 0, 0, 0);
        o = __builtin_amdgcn_mfma_f32_16x16x32_bf16(ga1, sb1, o, 0, 0, 0);
        const float bc = b_s[lr];
        const float d0 = ct * m00 + o[0] + bc - yv0;
        const float d1 = ct * m01 + o[1] + bc - yv1;
        const float d2 = ct * m02 + o[2] + bc - yv2;
        const float d3 = ct * m03 + o[3] + bc - yv3;
        s0 = CD * s0 - LRS * d0;
        s1 = CD * s1 - LRS * d1;
        s2 = CD * s2 - LRS * d2;
        s3 = CD * s3 - LRS * d3;
        ct *= CD;
        __syncthreads();                       // all waves done reading Ss this step
        short4 sp;
        sp.x = f2bf(s0); sp.y = f2bf(s1); sp.z = f2bf(s2); sp.w = f2bf(s3);
        *(short4*)(&Ss[lr * 72 + row0]) = sp;  // S^T[col][k]
        red[(wid * 4 + lg) * 16 + lr] = d0 + d1 + d2 + d3;
        __syncthreads();
        if (t < 16) {                          // bias update: colsum(diff)
            float a = 0.f;
            #pragma unroll
            for (int i = 0; i < 16; ++i) a += red[i * 16 + t];
            b_s[t] = CD * b_s[t] - LRS * a;
        }
        __syncthreads();
    }

    // ---------------- Final: logits = c^20*p0 + q^T S + b
    const float part = q_s[row0 + 0] * s0 + q_s[row0 + 1] * s1 +
                       q_s[row0 + 2] * s2 + q_s[row0 + 3] * s3;
    red[(wid * 4 + lg) * 16 + lr] = part;
    __syncthreads();
    if (t < 8) {
        float a = 0.f;
        #pragma unroll
        for (int i = 0; i < 16; ++i) a += red[i * 16 + t];
        out[b * LL + t] = ct * p0_s[t] + a + b_s[t];
    }
}

extern "C" void kernel_launch(void* const* d_in, const int* in_sizes, int n_in,
                              void* d_out, int out_size, void* d_ws, size_t ws_size,
                              hipStream_t stream) {
    const float* demo   = (const float*)d_in[0]; // demo_embeddings [512,64,1024]
    const float* emb    = (const float*)d_in[1]; // embeddings     [512,1024]
    const float* W0     = (const float*)d_in[2]; // W0             [512,8,1024]
    const float* b0     = (const float*)d_in[3]; // b0             [512,8]
    const int*   labels = (const int*)d_in[4];   // demo_labels    [512,64]
    float* out = (float*)d_out;                  // logits         [512,8] f32
    (void)in_sizes; (void)n_in; (void)out_size; (void)d_ws; (void)ws_size;
    hipLaunchKernelGGL(knn_linear_fix_kernel, dim3(BB), dim3(256), 0, stream,
                       demo, emb, W0, b0, labels, out);
}

// Round 2
// 35.564 us; speedup vs baseline: 1.1044x; 1.1044x over previous
//
#include <hip/hip_runtime.h>

// Problem constants (KnnLinearFixModel): B=512, K=64, D=1024, L=8, 20 SGD steps.
// Key identity: W_t = c^t*W0 + A_t*X  (c = 1-LR*WD), so only G=X*X^T, M0=X*W0^T,
// q=X*e, p0=W0*e are needed; the 20-step loop runs on 64x8 matrices on-chip.
// R2: 4-deep register prefetch pipeline in phase 1 (loads issue ~4 half-iters
// ahead of use -> streaming, not latency-serialized); phase 3 bias in registers
// (2 barriers/step instead of 3).

#define BB 512
#define KK 64
#define DD 1024
#define LL 8
#define NSTEPS 20

typedef __attribute__((ext_vector_type(8))) short bf16x8;
typedef __attribute__((ext_vector_type(4))) float f32x4;

__device__ __forceinline__ short f2bf(float f) {
    // round-to-nearest-even f32 -> bf16 (inputs are finite Gaussians; no NaN handling)
    unsigned u = __float_as_uint(f);
    unsigned r = (u + 0x7FFFu + ((u >> 16) & 1u)) >> 16;
    return (short)r;
}

struct Chunk {
    float4 x0, x1, x2, x3;  // X rows xr, xr+16, xr+32, xr+48
    float4 p;               // P row xr (W0 rows 0-7, e at row 8, zeros 9-15)
};

__global__ __launch_bounds__(256, 2)
void knn_linear_fix_kernel(const float* __restrict__ demo,   // [B,K,D]
                           const float* __restrict__ emb,    // [B,D]
                           const float* __restrict__ W0,     // [B,L,D]
                           const float* __restrict__ b0,     // [B,L]
                           const int*   __restrict__ labels, // [B,K]
                           float* __restrict__ out)          // [B,L]
{
    const int b    = blockIdx.x;
    const int t    = threadIdx.x;
    const int lane = t & 63;
    const int wid  = t >> 6;          // wave id 0..3
    const int lg   = lane >> 4;       // lane group 0..3
    const int lr   = lane & 15;       // low lane bits -> row (A) / col (B,C)

    const float LR  = 1e-4f;
    const float WD  = 0.01f;
    const float LRS = LR * (2.0f / (float)(KK * LL)); // LR*scale = 3.90625e-7
    const float CD  = 1.0f - LR * WD;                 // weight-decay contraction

    // LDS: stride 72 shorts (=144 B) breaks the 128B-stride bank pathology
    __shared__ short Xs[64 * 72];   // X chunk, bf16
    __shared__ short Ps[16 * 72];   // [W0 rows (8); e (1); zeros (7)] chunk, bf16
    __shared__ short Gs[64 * 72];   // G = X X^T, bf16
    __shared__ short Ss[16 * 72];   // S^T: [col][k-row], bf16
    __shared__ float red[256];      // cross-wave reduction buffer
    __shared__ float p0_s[16];      // p0 = W0 . e
    __shared__ float q_s[64];       // q  = X . e
    __shared__ int   lab_s[64];

    const float* Xg = demo + (size_t)b * (KK * DD);
    const float* Wg = W0   + (size_t)b * (LL * DD);
    const float* eg = emb  + (size_t)b * DD;

    if (t < 64) lab_s[t] = labels[b * KK + t];
    for (int i = t; i < 16 * 72; i += 256) Ss[i] = 0;

    // bias held in registers, replicated: every lane's bc is bias[lr]
    float bc = (lr < 8) ? b0[b * LL + lr] : 0.0f;

    // Gram accumulators: wave w owns G rows [16w,16w+16) x all 64 cols (4 tiles),
    // plus M tile (cols 0..7 = M0, col 8 = q) and P*P^T tile (for p0).
    f32x4 accG0 = {0,0,0,0}, accG1 = {0,0,0,0}, accG2 = {0,0,0,0}, accG3 = {0,0,0,0};
    f32x4 accM  = {0,0,0,0}, accPP = {0,0,0,0};

    const int xr = t >> 4;          // staging row 0..15
    const int xc = (t & 15) * 4;    // staging col (floats)

#define LOADX(buf, CH) do {                                                      \
        const int dk = (CH) * 64;                                                \
        (buf).x0 = *(const float4*)(Xg + (size_t)(xr     ) * DD + dk + xc);      \
        (buf).x1 = *(const float4*)(Xg + (size_t)(xr + 16) * DD + dk + xc);      \
        (buf).x2 = *(const float4*)(Xg + (size_t)(xr + 32) * DD + dk + xc);      \
        (buf).x3 = *(const float4*)(Xg + (size_t)(xr + 48) * DD + dk + xc);      \
        if (xr < 8)       (buf).p = *(const float4*)(Wg + (size_t)xr * DD + dk + xc); \
        else if (xr == 8) (buf).p = *(const float4*)(eg + dk + xc);              \
        else              (buf).p = make_float4(0.f, 0.f, 0.f, 0.f);             \
    } while (0)

#define STOREC(buf) do {                                                         \
        short4 h;                                                                \
        h.x = f2bf((buf).x0.x); h.y = f2bf((buf).x0.y);                          \
        h.z = f2bf((buf).x0.z); h.w = f2bf((buf).x0.w);                          \
        *(short4*)(&Xs[(xr     ) * 72 + xc]) = h;                                \
        h.x = f2bf((buf).x1.x); h.y = f2bf((buf).x1.y);                          \
        h.z = f2bf((buf).x1.z); h.w = f2bf((buf).x1.w);                          \
        *(short4*)(&Xs[(xr + 16) * 72 + xc]) = h;                                \
        h.x = f2bf((buf).x2.x); h.y = f2bf((buf).x2.y);                          \
        h.z = f2bf((buf).x2.z); h.w = f2bf((buf).x2.w);                          \
        *(short4*)(&Xs[(xr + 32) * 72 + xc]) = h;                                \
        h.x = f2bf((buf).x3.x); h.y = f2bf((buf).x3.y);                          \
        h.z = f2bf((buf).x3.z); h.w = f2bf((buf).x3.w);                          \
        *(short4*)(&Xs[(xr + 48) * 72 + xc]) = h;                                \
        h.x = f2bf((buf).p.x);  h.y = f2bf((buf).p.y);                           \
        h.z = f2bf((buf).p.z);  h.w = f2bf((buf).p.w);                           \
        *(short4*)(&Ps[xr * 72 + xc]) = h;                                       \
    } while (0)

#define MFMA_BODY() do {                                                         \
        _Pragma("unroll")                                                        \
        for (int ks = 0; ks < 2; ++ks) {                                         \
            const int ko = ks * 32 + lg * 8;                                     \
            const bf16x8 fa = *(const bf16x8*)(&Xs[(wid * 16 + lr) * 72 + ko]);  \
            const bf16x8 f0 = *(const bf16x8*)(&Xs[( 0 + lr) * 72 + ko]);        \
            const bf16x8 f1 = *(const bf16x8*)(&Xs[(16 + lr) * 72 + ko]);        \
            const bf16x8 f2 = *(const bf16x8*)(&Xs[(32 + lr) * 72 + ko]);        \
            const bf16x8 f3 = *(const bf16x8*)(&Xs[(48 + lr) * 72 + ko]);        \
            const bf16x8 fp = *(const bf16x8*)(&Ps[lr * 72 + ko]);               \
            accG0 = __builtin_amdgcn_mfma_f32_16x16x32_bf16(fa, f0, accG0, 0, 0, 0); \
            accG1 = __builtin_amdgcn_mfma_f32_16x16x32_bf16(fa, f1, accG1, 0, 0, 0); \
            accG2 = __builtin_amdgcn_mfma_f32_16x16x32_bf16(fa, f2, accG2, 0, 0, 0); \
            accG3 = __builtin_amdgcn_mfma_f32_16x16x32_bf16(fa, f3, accG3, 0, 0, 0); \
            accM  = __builtin_amdgcn_mfma_f32_16x16x32_bf16(fa, fp, accM , 0, 0, 0); \
            accPP = __builtin_amdgcn_mfma_f32_16x16x32_bf16(fp, fp, accPP, 0, 0, 0); \
        }                                                                        \
    } while (0)

    // ---------------- Phase 1: stream D in 16 chunks of 64, 4-deep prefetch
    Chunk c0, c1, c2, c3;
    LOADX(c0, 0); LOADX(c1, 1); LOADX(c2, 2); LOADX(c3, 3);
    for (int ch = 0; ch < 16; ch += 4) {
        STOREC(c0); __syncthreads();
        if (ch + 4 < 16) LOADX(c0, ch + 4);
        MFMA_BODY(); __syncthreads();

        STOREC(c1); __syncthreads();
        if (ch + 5 < 16) LOADX(c1, ch + 5);
        MFMA_BODY(); __syncthreads();

        STOREC(c2); __syncthreads();
        if (ch + 6 < 16) LOADX(c2, ch + 6);
        MFMA_BODY(); __syncthreads();

        STOREC(c3); __syncthreads();
        if (ch + 7 < 16) LOADX(c3, ch + 7);
        MFMA_BODY(); __syncthreads();
    }

    // ---------------- Phase 2: spill G (bf16), q, p0; C/D: row=(lg*4+r), col=lr
    #pragma unroll
    for (int r = 0; r < 4; ++r) {
        const int row = wid * 16 + lg * 4 + r;
        Gs[row * 72 +  0 + lr] = f2bf(accG0[r]);
        Gs[row * 72 + 16 + lr] = f2bf(accG1[r]);
        Gs[row * 72 + 32 + lr] = f2bf(accG2[r]);
        Gs[row * 72 + 48 + lr] = f2bf(accG3[r]);
    }
    if (lr == 8) {
        #pragma unroll
        for (int r = 0; r < 4; ++r) q_s[wid * 16 + lg * 4 + r] = accM[r];
    }
    if (wid == 0 && lg == 2) p0_s[lr] = accPP[0];   // row 8 of P*P^T = e . P[col]
    __syncthreads();

    // ---------------- Phase 3: 20-step SGD on 64x8 state, out = c^t*M0 + G*S + b
    const bf16x8 ga0 = *(const bf16x8*)(&Gs[(wid * 16 + lr) * 72 +  0 + lg * 8]);
    const bf16x8 ga1 = *(const bf16x8*)(&Gs[(wid * 16 + lr) * 72 + 32 + lg * 8]);

    const int row0 = wid * 16 + lg * 4;
    const float yv0 = (lab_s[row0 + 0] == lr) ? 1.0f : 0.0f;
    const float yv1 = (lab_s[row0 + 1] == lr) ? 1.0f : 0.0f;
    const float yv2 = (lab_s[row0 + 2] == lr) ? 1.0f : 0.0f;
    const float yv3 = (lab_s[row0 + 3] == lr) ? 1.0f : 0.0f;

    const float m00 = accM[0], m01 = accM[1], m02 = accM[2], m03 = accM[3];
    float s0 = 0.f, s1 = 0.f, s2 = 0.f, s3 = 0.f;
    float ct = 1.0f;

    for (int step = 0; step < NSTEPS; ++step) {
        const bf16x8 sb0 = *(const bf16x8*)(&Ss[lr * 72 +  0 + lg * 8]);
        const bf16x8 sb1 = *(const bf16x8*)(&Ss[lr * 72 + 32 + lg * 8]);
        f32x4 o = {0.f, 0.f, 0.f, 0.f};
        o = __builtin_amdgcn_mfma_f32_16x16x32_bf16(ga0, sb0, o, 0, 0, 0);
        o = __builtin_amdgcn_mfma_f32_16x16x32_bf16(ga1, sb1, o, 0, 0, 0);
        const float d0 = ct * m00 + o[0] + bc - yv0;
        const float d1 = ct * m01 + o[1] + bc - yv1;
        const float d2 = ct * m02 + o[2] + bc - yv2;
        const float d3 = ct * m03 + o[3] + bc - yv3;
        s0 = CD * s0 - LRS * d0;
        s1 = CD * s1 - LRS * d1;
        s2 = CD * s2 - LRS * d2;
        s3 = CD * s3 - LRS * d3;
        ct *= CD;
        // wave-local column sum over this wave's 16 rows (lg groups differ in
        // lane bits 4-5; lr preserved by xor 16/32 -> same output column)
        float colp = d0 + d1 + d2 + d3;
        colp += __shfl_xor(colp, 16, 64);
        colp += __shfl_xor(colp, 32, 64);
        __syncthreads();                       // all waves done reading Ss
        short4 sp;
        sp.x = f2bf(s0); sp.y = f2bf(s1); sp.z = f2bf(s2); sp.w = f2bf(s3);
        *(short4*)(&Ss[lr * 72 + row0]) = sp;  // S^T[col][k]
        if (lg == 0) red[wid * 16 + lr] = colp;
        __syncthreads();
        bc = CD * bc - LRS * (red[0 * 16 + lr] + red[1 * 16 + lr] +
                              red[2 * 16 + lr] + red[3 * 16 + lr]);
    }

    // ---------------- Final: logits = c^20*p0 + q^T S + b
    const float part = q_s[row0 + 0] * s0 + q_s[row0 + 1] * s1 +
                       q_s[row0 + 2] * s2 + q_s[row0 + 3] * s3;
    __syncthreads();                           // red rows 0..3 free to reuse
    red[(wid * 4 + lg) * 16 + lr] = part;
    __syncthreads();
    if (t < 8) {
        float a = 0.f;
        #pragma unroll
        for (int i = 0; i < 16; ++i) a += red[i * 16 + t];
        out[b * LL + t] = ct * p0_s[t] + a + bc;  // thread t: lr==t, so bc=bias[t]
    }
}

extern "C" void kernel_launch(void* const* d_in, const int* in_sizes, int n_in,
                              void* d_out, int out_size, void* d_ws, size_t ws_size,
                              hipStream_t stream) {
    const float* demo   = (const float*)d_in[0]; // demo_embeddings [512,64,1024]
    const float* emb    = (const float*)d_in[1]; // embeddings     [512,1024]
    const float* W0     = (const float*)d_in[2]; // W0             [512,8,1024]
    const float* b0     = (const float*)d_in[3]; // b0             [512,8]
    const int*   labels = (const int*)d_in[4];   // demo_labels    [512,64]
    float* out = (float*)d_out;                  // logits         [512,8] f32
    (void)in_sizes; (void)n_in; (void)out_size; (void)d_ws; (void)ws_size;
    hipLaunchKernelGGL(knn_linear_fix_kernel, dim3(BB), dim3(256), 0, stream,
                       demo, emb, W0, b0, labels, out);
}